// Round 1
// baseline (117.833 us; speedup 1.0000x reference)
//
#include <hip/hip_runtime.h>
#include <hip/hip_bf16.h>

// Problem constants
#define BDIM 1024
#define NCOL 1152      // 9 heads * 64 * 2 (q,k)
#define HEADS 9
#define HID 64
#define SLEN 512
#define BATCH 16
#define MROWS (BATCH*SLEN)   // 8192

typedef __attribute__((ext_vector_type(8))) short bf16x8;
typedef __attribute__((ext_vector_type(4))) float f32x4;

static __device__ __forceinline__ unsigned short f2bf(float f) {
    union { float f; unsigned int u; } x; x.f = f;
    unsigned int u = x.u;
    unsigned int r = (u + 0x7fffu + ((u >> 16) & 1u)) >> 16;
    return (unsigned short)r;
}

// ---------------------------------------------------------------------------
// Kernel 1: transpose+convert W [1024][1152] f32 -> Wt [1152][1024] bf16
// ---------------------------------------------------------------------------
__global__ __launch_bounds__(256) void wt_kernel(const float* __restrict__ W,
                                                 unsigned short* __restrict__ Wt) {
    __shared__ float tile[32][33];
    const int tx = threadIdx.x & 31;
    const int ty = threadIdx.x >> 5;          // 0..7
    const int nb = blockIdx.x * 32;           // over NCOL (36 blocks)
    const int kb = blockIdx.y * 32;           // over BDIM (32 blocks)
#pragma unroll
    for (int i = 0; i < 4; ++i) {
        int k = kb + ty + i * 8;
        tile[ty + i * 8][tx] = W[(size_t)k * NCOL + nb + tx];
    }
    __syncthreads();
#pragma unroll
    for (int i = 0; i < 4; ++i) {
        int n = nb + ty + i * 8;
        Wt[(size_t)n * BDIM + kb + tx] = f2bf(tile[tx][ty + i * 8]);
    }
}

// ---------------------------------------------------------------------------
// Kernel 2: RoPE sin/cos table  [512][32] float2 {sin, cos}
// ---------------------------------------------------------------------------
__global__ void sctab_kernel(float2* __restrict__ tab) {
    int idx = blockIdx.x * 256 + threadIdx.x;
    if (idx >= SLEN * (HID / 2)) return;
    int s = idx >> 5, j = idx & 31;
    float inv = powf(10000.0f, -(float)(2 * j) / (float)HID);
    float ang = (float)s * inv;
    tab[idx] = make_float2(sinf(ang), cosf(ang));
}

// ---------------------------------------------------------------------------
// Kernel 3: projection GEMM (8192x1024 @ 1024x1152) + bias + RoPE
// -> qk workspace bf16 [16][9][2][512][64]
// 128x128 tile, BK=32, 4 waves (2x2), each wave 64x64 (4x4 frags 16x16x32)
// ---------------------------------------------------------------------------
__global__ __launch_bounds__(256) void proj_rope_kernel(
    const float* __restrict__ hidden,        // [8192][1024]
    const unsigned short* __restrict__ Wt,   // [1152][1024] bf16
    const float* __restrict__ bias,          // [1152]
    const float2* __restrict__ sctab,        // [512][32]
    unsigned short* __restrict__ qk)         // [16][9][2][512][64] bf16
{
    // padded to 40 elements/row (80B): exact 2-way banks, 16B-aligned rows
    __shared__ __attribute__((aligned(16))) unsigned short As[128 * 40];
    __shared__ __attribute__((aligned(16))) unsigned short Bs[128 * 40];

    const int t = threadIdx.x;
    const int m0 = blockIdx.x * 128;
    const int n0 = blockIdx.y * 128;
    const int wid = t >> 6, lane = t & 63;
    const int wr = wid >> 1, wc = wid & 1;
    const int lrow = lane & 15;
    const int khalf = lane >> 4;

    f32x4 acc[4][4] = {};

    for (int k0 = 0; k0 < BDIM; k0 += 32) {
        // stage A: 128 rows x 32 f32 -> bf16
#pragma unroll
        for (int i = 0; i < 4; ++i) {
            int e = t + i * 256;              // 0..1023
            int row = e >> 3, kq = e & 7;     // 8 float4 per row
            float4 v = *reinterpret_cast<const float4*>(
                hidden + (size_t)(m0 + row) * BDIM + k0 + kq * 4);
            ushort4 p;
            p.x = f2bf(v.x); p.y = f2bf(v.y); p.z = f2bf(v.z); p.w = f2bf(v.w);
            *reinterpret_cast<ushort4*>(&As[row * 40 + kq * 4]) = p;
        }
        // stage B: 128 rows x 32 bf16 (already bf16)
#pragma unroll
        for (int i = 0; i < 2; ++i) {
            int e = t + i * 256;              // 0..511
            int row = e >> 2, c = e & 3;      // 4 x 16B per row
            uint4 v = *reinterpret_cast<const uint4*>(
                Wt + (size_t)(n0 + row) * BDIM + k0 + c * 8);
            *reinterpret_cast<uint4*>(&Bs[row * 40 + c * 8]) = v;
        }
        __syncthreads();

        bf16x8 af[4], bfr[4];
#pragma unroll
        for (int mi = 0; mi < 4; ++mi)
            af[mi] = *reinterpret_cast<const bf16x8*>(
                &As[(wr * 64 + mi * 16 + lrow) * 40 + khalf * 8]);
#pragma unroll
        for (int ni = 0; ni < 4; ++ni)
            bfr[ni] = *reinterpret_cast<const bf16x8*>(
                &Bs[(wc * 64 + ni * 16 + lrow) * 40 + khalf * 8]);
#pragma unroll
        for (int mi = 0; mi < 4; ++mi)
#pragma unroll
            for (int ni = 0; ni < 4; ++ni)
                acc[mi][ni] = __builtin_amdgcn_mfma_f32_16x16x32_bf16(
                    af[mi], bfr[ni], acc[mi][ni], 0, 0, 0);
        __syncthreads();
    }

    // epilogue: bias + RoPE + store bf16 to qk[b][h][qk][s][d]
#pragma unroll
    for (int ni = 0; ni < 4; ++ni) {
        int c = n0 + wc * 64 + ni * 16 + lrow;   // global column
        float bv = bias[c];
        int h = c >> 7;
        int r = c & 127;
        int qki = (r >> 6) & 1;
        int d = r & 63;
        int j = d >> 1;
        bool even = (d & 1) == 0;
#pragma unroll
        for (int mi = 0; mi < 4; ++mi) {
#pragma unroll
            for (int reg = 0; reg < 4; ++reg) {
                int m = m0 + wr * 64 + mi * 16 + khalf * 4 + reg;
                int bi = m >> 9, s = m & 511;
                float v = acc[mi][ni][reg] + bv;
                float p = __shfl_xor(v, 1);
                float2 sc = sctab[s * 32 + j];
                float o = even ? (v * sc.y - p * sc.x)
                               : (v * sc.y + p * sc.x);
                size_t off = ((((size_t)bi * HEADS + h) * 2 + qki) * SLEN + s) * HID + d;
                qk[off] = f2bf(o);
            }
        }
    }
}

// ---------------------------------------------------------------------------
// Kernel 4: logits[b,h,m,n] = (q.k * pad - (1-pad)*1e12) / 8
// per (b,h): 512x64 @ 64x512; grid (4,4,144), 128x128 tiles
// ---------------------------------------------------------------------------
__global__ __launch_bounds__(256) void logits_kernel(
    const unsigned short* __restrict__ qkbuf,  // [16][9][2][512][64] bf16
    const float* __restrict__ mask,            // [16][512]
    float* __restrict__ out)                   // [16][9][512][512]
{
    __shared__ __attribute__((aligned(16))) unsigned short Qs[128 * 72];
    __shared__ __attribute__((aligned(16))) unsigned short Ks[128 * 72];

    const int t = threadIdx.x;
    const int bz = blockIdx.z;                 // b*9 + h
    const int bi = bz / 9;
    const int m0 = blockIdx.x * 128, n0 = blockIdx.y * 128;

    const unsigned short* Qg = qkbuf + ((size_t)bz * 2 + 0) * SLEN * HID + (size_t)m0 * HID;
    const unsigned short* Kg = qkbuf + ((size_t)bz * 2 + 1) * SLEN * HID + (size_t)n0 * HID;

#pragma unroll
    for (int i = 0; i < 4; ++i) {
        int e = t + i * 256;                   // 0..1023
        int row = e >> 3, c = e & 7;           // 8 x 16B per 64-elem row
        *reinterpret_cast<uint4*>(&Qs[row * 72 + c * 8]) =
            *reinterpret_cast<const uint4*>(Qg + (size_t)row * HID + c * 8);
        *reinterpret_cast<uint4*>(&Ks[row * 72 + c * 8]) =
            *reinterpret_cast<const uint4*>(Kg + (size_t)row * HID + c * 8);
    }
    __syncthreads();

    const int wid = t >> 6, lane = t & 63;
    const int wr = wid >> 1, wc = wid & 1;
    const int lrow = lane & 15;
    const int khalf = lane >> 4;

    f32x4 acc[4][4] = {};
#pragma unroll
    for (int kk = 0; kk < 2; ++kk) {
        bf16x8 af[4], bfr[4];
#pragma unroll
        for (int mi = 0; mi < 4; ++mi)
            af[mi] = *reinterpret_cast<const bf16x8*>(
                &Qs[(wr * 64 + mi * 16 + lrow) * 72 + kk * 32 + khalf * 8]);
#pragma unroll
        for (int ni = 0; ni < 4; ++ni)
            bfr[ni] = *reinterpret_cast<const bf16x8*>(
                &Ks[(wc * 64 + ni * 16 + lrow) * 72 + kk * 32 + khalf * 8]);
#pragma unroll
        for (int mi = 0; mi < 4; ++mi)
#pragma unroll
            for (int ni = 0; ni < 4; ++ni)
                acc[mi][ni] = __builtin_amdgcn_mfma_f32_16x16x32_bf16(
                    af[mi], bfr[ni], acc[mi][ni], 0, 0, 0);
    }

#pragma unroll
    for (int ni = 0; ni < 4; ++ni) {
        int n = n0 + wc * 64 + ni * 16 + lrow;
        float pv = mask[bi * SLEN + n];
        float sub = (1.0f - pv) * 1000000000000.0f;
#pragma unroll
        for (int mi = 0; mi < 4; ++mi) {
#pragma unroll
            for (int reg = 0; reg < 4; ++reg) {
                int m = m0 + wr * 64 + mi * 16 + khalf * 4 + reg;
                float v = (acc[mi][ni][reg] * pv - sub) * 0.125f;
                out[((size_t)bz * SLEN + m) * SLEN + n] = v;
            }
        }
    }
}

// ---------------------------------------------------------------------------
extern "C" void kernel_launch(void* const* d_in, const int* in_sizes, int n_in,
                              void* d_out, int out_size, void* d_ws, size_t ws_size,
                              hipStream_t stream) {
    const float* hidden = (const float*)d_in[0];   // 16*512*1024
    const float* mask   = (const float*)d_in[1];   // 16*512
    const float* W      = (const float*)d_in[2];   // 1024*1152
    const float* bias   = (const float*)d_in[3];   // 1152
    float* out = (float*)d_out;

    char* ws = (char*)d_ws;
    unsigned short* Wt = (unsigned short*)ws;                       // 2,359,296 B
    float2* sctab = (float2*)(ws + 2359296);                        //   131,072 B
    unsigned short* qk = (unsigned short*)(ws + 2359296 + 131072);  // 18,874,368 B

    wt_kernel<<<dim3(36, 32), 256, 0, stream>>>(W, Wt);
    sctab_kernel<<<64, 256, 0, stream>>>(sctab);
    proj_rope_kernel<<<dim3(64, 9), 256, 0, stream>>>(hidden, Wt, bias, sctab, qk);
    logits_kernel<<<dim3(4, 4, BATCH * HEADS), 256, 0, stream>>>(qk, mask, out);
}

// Round 2
// 100.209 us; speedup vs baseline: 1.1759x; 1.1759x over previous
//
#include <hip/hip_runtime.h>
#include <hip/hip_bf16.h>

// Problem constants
#define BDIM 1024
#define NCOL 1152      // 9 heads * 64 * 2 (q,k)
#define HEADS 9
#define HID 64
#define SLEN 512
#define BATCH 16
#define MROWS (BATCH*SLEN)   // 8192

typedef __attribute__((ext_vector_type(8))) short bf16x8;
typedef __attribute__((ext_vector_type(8))) unsigned short u16x8;
typedef __attribute__((ext_vector_type(4))) float f32x4;

static __device__ __forceinline__ unsigned short f2bf(float f) {
    union { float f; unsigned int u; } x; x.f = f;
    unsigned int u = x.u;
    unsigned int r = (u + 0x7fffu + ((u >> 16) & 1u)) >> 16;
    return (unsigned short)r;
}

#define GLOAD_LDS16(g, l)                                                     \
    __builtin_amdgcn_global_load_lds(                                         \
        (const __attribute__((address_space(1))) unsigned int*)(g),           \
        (__attribute__((address_space(3))) unsigned int*)(l), 16, 0, 0)

// ---------------------------------------------------------------------------
// Kernel 0: convert hidden f32 -> bf16 (Ab [8192][1024])
// ---------------------------------------------------------------------------
__global__ __launch_bounds__(256) void conv_kernel(const float* __restrict__ in,
                                                   unsigned short* __restrict__ out) {
    int i = (blockIdx.x * 256 + threadIdx.x) * 8;   // 8.39M elems / 8 = 1M threads
    float4 a = *reinterpret_cast<const float4*>(in + i);
    float4 b = *reinterpret_cast<const float4*>(in + i + 4);
    u16x8 p;
    p[0] = f2bf(a.x); p[1] = f2bf(a.y); p[2] = f2bf(a.z); p[3] = f2bf(a.w);
    p[4] = f2bf(b.x); p[5] = f2bf(b.y); p[6] = f2bf(b.z); p[7] = f2bf(b.w);
    *reinterpret_cast<u16x8*>(out + i) = p;
}

// ---------------------------------------------------------------------------
// Kernel 1: transpose+convert W [1024][1152] f32 -> Wt [1152][1024] bf16
// ---------------------------------------------------------------------------
__global__ __launch_bounds__(256) void wt_kernel(const float* __restrict__ W,
                                                 unsigned short* __restrict__ Wt) {
    __shared__ float tile[32][33];
    const int tx = threadIdx.x & 31;
    const int ty = threadIdx.x >> 5;          // 0..7
    const int nb = blockIdx.x * 32;           // over NCOL (36 blocks)
    const int kb = blockIdx.y * 32;           // over BDIM (32 blocks)
#pragma unroll
    for (int i = 0; i < 4; ++i) {
        int k = kb + ty + i * 8;
        tile[ty + i * 8][tx] = W[(size_t)k * NCOL + nb + tx];
    }
    __syncthreads();
#pragma unroll
    for (int i = 0; i < 4; ++i) {
        int n = nb + ty + i * 8;
        Wt[(size_t)n * BDIM + kb + tx] = f2bf(tile[tx][ty + i * 8]);
    }
}

// ---------------------------------------------------------------------------
// Kernel 2: RoPE sin/cos table  [512][32] float2 {sin, cos}
// ---------------------------------------------------------------------------
__global__ void sctab_kernel(float2* __restrict__ tab) {
    int idx = blockIdx.x * 256 + threadIdx.x;
    if (idx >= SLEN * (HID / 2)) return;
    int s = idx >> 5, j = idx & 31;
    float inv = powf(10000.0f, -(float)(2 * j) / (float)HID);
    float ang = (float)s * inv;
    tab[idx] = make_float2(sinf(ang), cosf(ang));
}

// ---------------------------------------------------------------------------
// Kernel 3: projection GEMM (8192x1024 @ 1024x1152, both bf16) + bias + RoPE
// -> qk workspace bf16 [16][9][2][512][64]
// m97 structure: 128x128 tile, BK=32, linear LDS, global_load_lds width=16,
// 4 waves (2x2), each wave 64x64 (4x4 frags of 16x16x32)
// ---------------------------------------------------------------------------
__global__ __launch_bounds__(256) void proj_rope_kernel(
    const unsigned short* __restrict__ Ab,   // [8192][1024] bf16
    const unsigned short* __restrict__ Wt,   // [1152][1024] bf16
    const float* __restrict__ bias,          // [1152]
    const float2* __restrict__ sctab,        // [512][32]
    unsigned short* __restrict__ qk)         // [16][9][2][512][64] bf16
{
    __shared__ __attribute__((aligned(16))) unsigned short As[128 * 32]; // 8 KB
    __shared__ __attribute__((aligned(16))) unsigned short Bs[128 * 32]; // 8 KB

    const int t = threadIdx.x;
    const int m0 = blockIdx.x * 128;
    const int n0 = blockIdx.y * 128;
    const int wid = t >> 6, lane = t & 63;
    const int wr = wid >> 1, wc = wid & 1;
    const int lrow = lane & 15;
    const int khalf = lane >> 4;

    // staging geometry: issue i covers bytes [i*4096 + wid*1024 + lane*16)
    // row = i*64 + wid*16 + (lane>>2), col elems = (lane&3)*8
    const int srow = wid * 16 + (lane >> 2);
    const int scol = (lane & 3) * 8;
    const unsigned short* gA = Ab + (size_t)(m0 + srow) * BDIM + scol;
    const unsigned short* gB = Wt + (size_t)(n0 + srow) * BDIM + scol;
    unsigned short* lA = As + wid * 512;   // elem offset of wave chunk
    unsigned short* lB = Bs + wid * 512;

    f32x4 acc[4][4] = {};

    for (int k0 = 0; k0 < BDIM; k0 += 32) {
        GLOAD_LDS16(gA + k0,              lA);
        GLOAD_LDS16(gA + k0 + 64 * BDIM,  lA + 2048);
        GLOAD_LDS16(gB + k0,              lB);
        GLOAD_LDS16(gB + k0 + 64 * BDIM,  lB + 2048);
        __syncthreads();

        bf16x8 af[4], bfr[4];
#pragma unroll
        for (int mi = 0; mi < 4; ++mi)
            af[mi] = *reinterpret_cast<const bf16x8*>(
                &As[(wr * 64 + mi * 16 + lrow) * 32 + khalf * 8]);
#pragma unroll
        for (int ni = 0; ni < 4; ++ni)
            bfr[ni] = *reinterpret_cast<const bf16x8*>(
                &Bs[(wc * 64 + ni * 16 + lrow) * 32 + khalf * 8]);
#pragma unroll
        for (int mi = 0; mi < 4; ++mi)
#pragma unroll
            for (int ni = 0; ni < 4; ++ni)
                acc[mi][ni] = __builtin_amdgcn_mfma_f32_16x16x32_bf16(
                    af[mi], bfr[ni], acc[mi][ni], 0, 0, 0);
        __syncthreads();
    }

    // epilogue: bias + RoPE + store bf16 to qk[b][h][qk][s][d]
#pragma unroll
    for (int ni = 0; ni < 4; ++ni) {
        int c = n0 + wc * 64 + ni * 16 + lrow;   // global column
        float bv = bias[c];
        int h = c >> 7;
        int r = c & 127;
        int qki = (r >> 6) & 1;
        int d = r & 63;
        int j = d >> 1;
        bool even = (d & 1) == 0;
#pragma unroll
        for (int mi = 0; mi < 4; ++mi) {
#pragma unroll
            for (int reg = 0; reg < 4; ++reg) {
                int m = m0 + wr * 64 + mi * 16 + khalf * 4 + reg;
                int bi = m >> 9, s = m & 511;
                float v = acc[mi][ni][reg] + bv;
                float p = __shfl_xor(v, 1);
                float2 sc = sctab[s * 32 + j];
                float o = even ? (v * sc.y - p * sc.x)
                               : (v * sc.y + p * sc.x);
                size_t off = ((((size_t)bi * HEADS + h) * 2 + qki) * SLEN + s) * HID + d;
                qk[off] = f2bf(o);
            }
        }
    }
}

// ---------------------------------------------------------------------------
// Kernel 4: logits[b,h,m,n] = (q.k * pad - (1-pad)*1e12) / 8
// per (b,h): 512x64 @ 64x512; grid (4,4,144), 128x128 tiles
// ---------------------------------------------------------------------------
__global__ __launch_bounds__(256) void logits_kernel(
    const unsigned short* __restrict__ qkbuf,  // [16][9][2][512][64] bf16
    const float* __restrict__ mask,            // [16][512]
    float* __restrict__ out)                   // [16][9][512][512]
{
    __shared__ __attribute__((aligned(16))) unsigned short Qs[128 * 72];
    __shared__ __attribute__((aligned(16))) unsigned short Ks[128 * 72];

    const int t = threadIdx.x;
    const int bz = blockIdx.z;                 // b*9 + h
    const int bi = bz / 9;
    const int m0 = blockIdx.x * 128, n0 = blockIdx.y * 128;

    const unsigned short* Qg = qkbuf + ((size_t)bz * 2 + 0) * SLEN * HID + (size_t)m0 * HID;
    const unsigned short* Kg = qkbuf + ((size_t)bz * 2 + 1) * SLEN * HID + (size_t)n0 * HID;

#pragma unroll
    for (int i = 0; i < 4; ++i) {
        int e = t + i * 256;                   // 0..1023
        int row = e >> 3, c = e & 7;           // 8 x 16B per 64-elem row
        *reinterpret_cast<uint4*>(&Qs[row * 72 + c * 8]) =
            *reinterpret_cast<const uint4*>(Qg + (size_t)row * HID + c * 8);
        *reinterpret_cast<uint4*>(&Ks[row * 72 + c * 8]) =
            *reinterpret_cast<const uint4*>(Kg + (size_t)row * HID + c * 8);
    }
    __syncthreads();

    const int wid = t >> 6, lane = t & 63;
    const int wr = wid >> 1, wc = wid & 1;
    const int lrow = lane & 15;
    const int khalf = lane >> 4;

    f32x4 acc[4][4] = {};
#pragma unroll
    for (int kk = 0; kk < 2; ++kk) {
        bf16x8 af[4], bfr[4];
#pragma unroll
        for (int mi = 0; mi < 4; ++mi)
            af[mi] = *reinterpret_cast<const bf16x8*>(
                &Qs[(wr * 64 + mi * 16 + lrow) * 72 + kk * 32 + khalf * 8]);
#pragma unroll
        for (int ni = 0; ni < 4; ++ni)
            bfr[ni] = *reinterpret_cast<const bf16x8*>(
                &Ks[(wc * 64 + ni * 16 + lrow) * 72 + kk * 32 + khalf * 8]);
#pragma unroll
        for (int mi = 0; mi < 4; ++mi)
#pragma unroll
            for (int ni = 0; ni < 4; ++ni)
                acc[mi][ni] = __builtin_amdgcn_mfma_f32_16x16x32_bf16(
                    af[mi], bfr[ni], acc[mi][ni], 0, 0, 0);
    }

#pragma unroll
    for (int ni = 0; ni < 4; ++ni) {
        int n = n0 + wc * 64 + ni * 16 + lrow;
        float pv = mask[bi * SLEN + n];
        float sub = (1.0f - pv) * 1000000000000.0f;
#pragma unroll
        for (int mi = 0; mi < 4; ++mi) {
#pragma unroll
            for (int reg = 0; reg < 4; ++reg) {
                int m = m0 + wr * 64 + mi * 16 + khalf * 4 + reg;
                float v = (acc[mi][ni][reg] * pv - sub) * 0.125f;
                out[((size_t)bz * SLEN + m) * SLEN + n] = v;
            }
        }
    }
}

// ---------------------------------------------------------------------------
extern "C" void kernel_launch(void* const* d_in, const int* in_sizes, int n_in,
                              void* d_out, int out_size, void* d_ws, size_t ws_size,
                              hipStream_t stream) {
    const float* hidden = (const float*)d_in[0];   // 16*512*1024
    const float* mask   = (const float*)d_in[1];   // 16*512
    const float* W      = (const float*)d_in[2];   // 1024*1152
    const float* bias   = (const float*)d_in[3];   // 1152
    float* out = (float*)d_out;

    char* ws = (char*)d_ws;
    unsigned short* Ab = (unsigned short*)ws;                        // 16,777,216 B
    unsigned short* Wt = (unsigned short*)(ws + 16777216);           //  2,359,296 B
    float2* sctab = (float2*)(ws + 16777216 + 2359296);              //    131,072 B
    unsigned short* qk = (unsigned short*)(ws + 16777216 + 2359296 + 131072); // 18,874,368 B

    conv_kernel<<<MROWS * BDIM / (256 * 8), 256, 0, stream>>>(hidden, Ab);
    wt_kernel<<<dim3(36, 32), 256, 0, stream>>>(W, Wt);
    sctab_kernel<<<64, 256, 0, stream>>>(sctab);
    proj_rope_kernel<<<dim3(64, 9), 256, 0, stream>>>(Ab, Wt, bias, sctab, qk);
    logits_kernel<<<dim3(4, 4, BATCH * HEADS), 256, 0, stream>>>(qk, mask, out);
}